// Round 20
// baseline (106.926 us; speedup 1.0000x reference)
//
#include <hip/hip_runtime.h>
#include <stdint.h>

typedef unsigned short u16;
typedef __attribute__((ext_vector_type(8))) short short8;
typedef __attribute__((ext_vector_type(4))) float f32x4;

#define B_      16
#define L_      1024
#define H_      1024
#define G_      128
#define M_TOT   16368            // B*(L-1)
#define K_TOT   3072
#define OUT_SEG 2095104          // M_TOT*G_
#define KL_IDX  (4*OUT_SEG)
#define KL_BLOCKS 2046           // M_TOT / 8 exactly

// ws layout
#define WS_WT_OFF    0           // bf16 W'T [512][3072] = 3,145,728 B
#define WS_BIAS_OFF  3145728     // float[512]
#define WS_PART_OFF  3147776     // float[2046] block partials

__device__ inline u16 f2bf(float f) {
    union { float f; uint32_t u; } x; x.f = f;
    uint32_t u = x.u;
    return (u16)((u + 0x7fffu + ((u >> 16) & 1u)) >> 16);
}

__device__ inline void gload16(const void* g, void* l) {
    __builtin_amdgcn_global_load_lds(
        (const __attribute__((address_space(1))) void*)g,
        (__attribute__((address_space(3))) void*)l, 16, 0, 0);
}

// ---------------- prep: build W'T (bf16, [512][3072]) + bias[512] ------------
// (R19 transposed-tile version, unchanged)
__global__ __launch_bounds__(256) void prep_kernel(
    const float* __restrict__ Wzm, const float* __restrict__ bzm,
    const float* __restrict__ Wzv, const float* __restrict__ bzv,
    const float* __restrict__ Wqm, const float* __restrict__ bqm,
    const float* __restrict__ Wqv, const float* __restrict__ bqv,
    u16* __restrict__ wt, float* __restrict__ bias)
{
    const int ng = blockIdx.x >> 2;
    const int kq = blockIdx.x & 3;
    const int n0 = ng * 8;
    const float* W; const float* bsrc; int g0; int kmax;
    if (n0 < 128)      { W = Wzm; bsrc = bzm; g0 = n0;       kmax = 2048; }
    else if (n0 < 256) { W = Wzv; bsrc = bzv; g0 = n0 - 128; kmax = 2048; }
    else if (n0 < 384) { W = Wqm; bsrc = bqm; g0 = n0 - 256; kmax = 3072; }
    else               { W = Wqv; bsrc = bqv; g0 = n0 - 384; kmax = 3072; }
    const int tid = threadIdx.x;
    if (kq == 0 && tid < 8) bias[n0 + tid] = bsrc[g0 + tid];

    __shared__ float lt[8][260];
    const int go = tid & 7;
    const int kk = tid >> 3;
    const int nn = tid >> 5;
    const int kc = (tid & 31) * 8;

    for (int i = 0; i < 3; ++i) {
        int kbase = kq * 768 + i * 256;
        __syncthreads();
        #pragma unroll
        for (int kk2 = 0; kk2 < 8; ++kk2) {
            int k = kbase + kk2 * 32 + kk;
            float v = (k < kmax) ? W[(size_t)k * G_ + g0 + go] : 0.0f;
            lt[go][kk2 * 32 + kk] = v;
        }
        __syncthreads();
        union { short8 s; u16 u[8]; } o;
        #pragma unroll
        for (int j = 0; j < 8; ++j) o.u[j] = f2bf(lt[nn][kc + j]);
        *(short8*)&wt[(size_t)(n0 + nn) * K_TOT + kbase + kc] = o.s;
    }
}

// ---------------- GEMM: out[m, 0:512] = ce @ W' + bias ----------------------
// BM=128, BN=128, BK=32, 96 tiles, 4 waves (2x2 of 64x64), grid 512
// -> 2 blocks/CU. 4-deep ring (A 8KB + B 8KB per tile = 64KB).
// ONE barrier per micro-phase: {LOADA(t+2); stageB(t+2); WAITV(8); LGKM0;
// BAR; compute(t); CVTW(t+1)} -- CVTW unfenced, drains at next LGKM0.
// Superrow LDS layout (both A,B): tile [64 sr][64 u16]; elem(row,k):
//   sr=row>>1, c=(row&1)*4+(k>>3), c'=c^(sr&7), off = sr*64 + c'*8 + (k&7).
// All b128 reads/writes land 2 lanes per bank-quad = conflict-free.
__global__ __launch_bounds__(256, 2) void gemm_kernel(
    const float* __restrict__ events, const float* __restrict__ contexts,
    const u16* __restrict__ wt, const float* __restrict__ bias,
    float* __restrict__ out)
{
    __shared__ u16 Ab[4][64 * 64];    // bf16 A tiles (8 KB each)
    __shared__ u16 Bs[4][64 * 64];    // bf16 B tiles (8 KB each)

    const int tid = threadIdx.x;
    const int bid = blockIdx.x;
    // 4 nb-blocks of an A panel share bid&7 -> same XCD.
    const int xx  = bid & 7;
    const int jj  = bid >> 3;            // 0..63
    const int nb  = jj & 3;
    const int mp  = (jj >> 2) * 8 + xx;  // 0..127
    const int m0  = mp * 128;

    const int lane = tid & 63;
    const int w    = tid >> 6;           // 0..3
    const int wm   = (w >> 1) * 64;
    const int wn   = (w & 1) * 64;
    const int lr   = lane & 15;
    const int kg   = lane >> 4;          // octet 0..3

    // ---- A staging: thread -> row r=tid>>1, half h=tid&1 (16 floats) ----
    const int r = tid >> 1;
    const int h = tid & 1;
    int m = m0 + r; if (m > M_TOT - 1) m = M_TOT - 1;
    int bb = m / 1023;
    int tt = m - bb * 1023;
    const float* paE = events   + ((size_t)(bb * L_ + tt)) * H_;
    const float* paC = contexts + ((size_t)(bb * (L_ - 1) + tt)) * H_;
    // superrow write offsets: octets o=2h, 2h+1; c=(r&1)*4+o; c'=c^(sr&7)
    const int srA  = r >> 1;
    const int aw0  = srA * 64 + ((((r & 1) * 4 + 2 * h)     ^ (srA & 7)) << 3);
    const int aw1  = srA * 64 + ((((r & 1) * 4 + 2 * h + 1) ^ (srA & 7)) << 3);

    // ---- B staging: 2 chunks/thread, source-preswizzled for superrow ----
    const u16* bS[2];
    #pragma unroll
    for (int it = 0; it < 2; ++it) {
        int cl = it * 256 + tid;         // 0..511
        int sr = cl >> 3;
        int cp = cl & 7;
        int c  = cp ^ (sr & 7);
        int v  = sr * 2 + (c >> 2);
        int kc = c & 3;
        bS[it] = wt + (size_t)(nb * 128 + v) * K_TOT + kc * 8;
    }

    // ---- fragment read offsets (u16, superrow) ----
    int aoff[4], boff[4];
    #pragma unroll
    for (int i = 0; i < 4; ++i) {
        int row = wm + i * 16 + lr;
        aoff[i] = (row >> 1) * 64 + ((((row & 1) * 4 + kg) ^ ((row >> 1) & 7)) << 3);
        int nn  = wn + i * 16 + lr;
        boff[i] = (nn >> 1) * 64 + ((((nn & 1) * 4 + kg) ^ ((nn >> 1) & 7)) << 3);
    }

    f32x4 acc[4][4];
    #pragma unroll
    for (int i = 0; i < 4; ++i)
        #pragma unroll
        for (int j = 0; j < 4; ++j)
            acc[i][j] = (f32x4){0.f, 0.f, 0.f, 0.f};

    // Named A-staging sets (2-phase pipeline; no arrays -> no scratch)
    f32x4 P0, P1, P2, P3;
    f32x4 Q0, Q1, Q2, Q3;

#define LOADA(p, KT)                                                           \
    {                                                                          \
        int rg_ = (KT) >> 5;                                                   \
        int kq_ = (((KT) & 31) << 5) + h * 16;                                 \
        const float* s_ = (rg_ == 0) ? paE : (rg_ == 1 ? (paE + H_) : paC);    \
        s_ += kq_;                                                             \
        p##0 = *(const f32x4*)(s_ +  0);                                       \
        p##1 = *(const f32x4*)(s_ +  4);                                       \
        p##2 = *(const f32x4*)(s_ +  8);                                       \
        p##3 = *(const f32x4*)(s_ + 12);                                       \
    }
#define STAGEB(BUF, KT)                                                        \
    {                                                                          \
        gload16(bS[0] + (KT) * 32, &Bs[BUF][tid * 8]);                         \
        gload16(bS[1] + (KT) * 32, &Bs[BUF][(256 + tid) * 8]);                 \
    }
#define CVTW(p, BUF)                                                           \
    {                                                                          \
        union { short8 v; uint32_t u[4]; } w0_, w1_;                           \
        asm("v_cvt_pk_bf16_f32 %0, %1, %2" : "=v"(w0_.u[0]) : "v"(p##0[0]), "v"(p##0[1])); \
        asm("v_cvt_pk_bf16_f32 %0, %1, %2" : "=v"(w0_.u[1]) : "v"(p##0[2]), "v"(p##0[3])); \
        asm("v_cvt_pk_bf16_f32 %0, %1, %2" : "=v"(w0_.u[2]) : "v"(p##1[0]), "v"(p##1[1])); \
        asm("v_cvt_pk_bf16_f32 %0, %1, %2" : "=v"(w0_.u[3]) : "v"(p##1[2]), "v"(p##1[3])); \
        asm("v_cvt_pk_bf16_f32 %0, %1, %2" : "=v"(w1_.u[0]) : "v"(p##2[0]), "v"(p##2[1])); \
        asm("v_cvt_pk_bf16_f32 %0, %1, %2" : "=v"(w1_.u[1]) : "v"(p##2[2]), "v"(p##2[3])); \
        asm("v_cvt_pk_bf16_f32 %0, %1, %2" : "=v"(w1_.u[2]) : "v"(p##3[0]), "v"(p##3[1])); \
        asm("v_cvt_pk_bf16_f32 %0, %1, %2" : "=v"(w1_.u[3]) : "v"(p##3[2]), "v"(p##3[3])); \
        *(short8*)&Ab[BUF][aw0] = w0_.v;                                       \
        *(short8*)&Ab[BUF][aw1] = w1_.v;                                       \
    }
#define COMPUTE(BUF)                                                           \
    {                                                                          \
        short8 a_[4], b_[4];                                                   \
        _Pragma("unroll")                                                      \
        for (int i = 0; i < 4; ++i) a_[i] = *(const short8*)&Ab[BUF][aoff[i]]; \
        _Pragma("unroll")                                                      \
        for (int j = 0; j < 4; ++j) b_[j] = *(const short8*)&Bs[BUF][boff[j]]; \
        __builtin_amdgcn_s_setprio(1);                                         \
        _Pragma("unroll")                                                      \
        for (int i = 0; i < 4; ++i)                                            \
            _Pragma("unroll")                                                  \
            for (int j = 0; j < 4; ++j)                                        \
                acc[i][j] = __builtin_amdgcn_mfma_f32_16x16x32_bf16(           \
                    a_[i], b_[j], acc[i][j], 0, 0, 0);                         \
        __builtin_amdgcn_s_setprio(0);                                         \
    }

#define WAITV(N)                                                               \
    asm volatile("s_waitcnt vmcnt(" #N ")" ::: "memory");                      \
    __builtin_amdgcn_sched_barrier(0);
#define LGKM0                                                                  \
    asm volatile("s_waitcnt lgkmcnt(0)" ::: "memory");                         \
    __builtin_amdgcn_sched_barrier(0);
#define BARS                                                                   \
    __builtin_amdgcn_s_barrier();                                              \
    __builtin_amdgcn_sched_barrier(0);

// PHASE p: compute buf p&3, CVTW -> (p+1)&3, stage -> (p+2)&3,
//          load set = (p even ? P : Q), cvt set = the other.
#define PHASE(KT, BC, BV, BS2, PL, PC)                                         \
    LOADA(PL, (KT) + 2);                                                       \
    STAGEB(BS2, (KT) + 2);                                                     \
    WAITV(8); LGKM0; BARS;                                                     \
    COMPUTE(BC);                                                               \
    CVTW(PC, BV);

    // prologue: tile0 -> Ab[0]/Bs[0]; A(1) -> Q; B(1) staged
    LOADA(P, 0);
    STAGEB(0, 0);
    WAITV(2);            // drain A(0) regs, leave B(0)
    CVTW(P, 0);
    LOADA(Q, 1);
    STAGEB(1, 1);
    LGKM0;               // prologue ds_writes drained; queue = B0,A1,B1 = 8

    for (int t = 0; t < 92; t += 4) {
        PHASE(t,     0, 1, 2, P, Q);
        PHASE(t + 1, 1, 2, 3, Q, P);
        PHASE(t + 2, 2, 3, 0, P, Q);
        PHASE(t + 3, 3, 0, 1, Q, P);
    }
    PHASE(92, 0, 1, 2, P, Q);
    PHASE(93, 1, 2, 3, Q, P);
    // phase 94: no issue; queue = B(94),A(95),B(95) = 8 -> drain B94+A95
    WAITV(2); LGKM0; BARS;
    COMPUTE(2);
    CVTW(Q, 3);
    // phase 95
    WAITV(0); LGKM0; BARS;
    COMPUTE(3);

#undef PHASE
#undef LOADA
#undef STAGEB
#undef CVTW
#undef COMPUTE
#undef WAITV
#undef LGKM0
#undef BARS

    // epilogue: row = m0 + wm + i*16 + kg*4 + rr ; gcol = nb*128 + wn + j*16 + lr
    const float* bptr = bias + nb * 128;
    float* obase = out + (size_t)nb * OUT_SEG;
    #pragma unroll
    for (int i = 0; i < 4; ++i) {
        int mloc = wm + i * 16 + kg * 4;
        #pragma unroll
        for (int j = 0; j < 4; ++j) {
            int g = wn + j * 16 + lr;
            float bv = bptr[g];
            #pragma unroll
            for (int rr = 0; rr < 4; ++rr) {
                int mo = m0 + mloc + rr;
                if (mo < M_TOT) obase[(size_t)mo * G_ + g] = acc[i][j][rr] + bv;
            }
        }
    }
}

// ---------------- KL reduction: stage 1 (f32x4 loads, 8 rows/block) ----------
__global__ __launch_bounds__(256) void kl_kernel(const float* __restrict__ out,
                                                 float* __restrict__ partial)
{
    int row  = blockIdx.x * 8 + (threadIdx.x >> 5);   // 2046*8 = M_TOT
    int col  = (threadIdx.x & 31) * 4;
    const float* zm  = out;
    const float* zlv = out + OUT_SEG;
    const float* qm  = out + (size_t)2 * OUT_SEG;
    const float* qlv = out + (size_t)3 * OUT_SEG;
    size_t base = (size_t)row * G_ + col;
    f32x4 a = *(const f32x4*)&zm[base];
    f32x4 b = *(const f32x4*)&zlv[base];
    f32x4 c = *(const f32x4*)&qm[base];
    f32x4 d = *(const f32x4*)&qlv[base];
    float s = 0.f;
    #pragma unroll
    for (int e = 0; e < 4; ++e) {
        float diff = a[e] - c[e];
        s += d[e] - b[e] + (__expf(b[e]) + diff * diff) * __expf(-d[e]) - 1.0f;
    }
    #pragma unroll
    for (int off = 32; off > 0; off >>= 1)
        s += __shfl_down(s, off);
    __shared__ float pw[4];
    int wid  = threadIdx.x >> 6;
    int lane = threadIdx.x & 63;
    if (lane == 0) pw[wid] = s;
    __syncthreads();
    if (threadIdx.x == 0)
        partial[blockIdx.x] = pw[0] + pw[1] + pw[2] + pw[3];
}

// ---------------- KL reduction: stage 2 --------------------------------------
__global__ __launch_bounds__(256) void kl_final(const float* __restrict__ partial,
                                                float* __restrict__ out)
{
    float s = 0.f;
    for (int i = threadIdx.x; i < KL_BLOCKS; i += 256) s += partial[i];
    #pragma unroll
    for (int off = 32; off > 0; off >>= 1)
        s += __shfl_down(s, off);
    __shared__ float pw[4];
    int wid = threadIdx.x >> 6;
    int lane = threadIdx.x & 63;
    if (lane == 0) pw[wid] = s;
    __syncthreads();
    if (threadIdx.x == 0)
        out[KL_IDX] = 0.5f * (pw[0] + pw[1] + pw[2] + pw[3]) / (float)M_TOT;
}

// ---------------- launcher ----------------------------------------------------
extern "C" void kernel_launch(void* const* d_in, const int* in_sizes, int n_in,
                              void* d_out, int out_size, void* d_ws, size_t ws_size,
                              hipStream_t stream)
{
    const float* events   = (const float*)d_in[0];
    const float* contexts = (const float*)d_in[1];
    const float* Wzm = (const float*)d_in[2];
    const float* bzm = (const float*)d_in[3];
    const float* Wzv = (const float*)d_in[4];
    const float* bzv = (const float*)d_in[5];
    const float* Wqm = (const float*)d_in[6];
    const float* bqm = (const float*)d_in[7];
    const float* Wqv = (const float*)d_in[8];
    const float* bqv = (const float*)d_in[9];
    float* out = (float*)d_out;

    u16*   wt      = (u16*)((char*)d_ws + WS_WT_OFF);
    float* bias    = (float*)((char*)d_ws + WS_BIAS_OFF);
    float* partial = (float*)((char*)d_ws + WS_PART_OFF);

    prep_kernel<<<256, 256, 0, stream>>>(Wzm, bzm, Wzv, bzv, Wqm, bqm, Wqv, bqv,
                                         wt, bias);
    gemm_kernel<<<512, 256, 0, stream>>>(events, contexts, wt, bias, out);
    kl_kernel<<<KL_BLOCKS, 256, 0, stream>>>(out, partial);
    kl_final<<<1, 256, 0, stream>>>(partial, out);
}

// Round 21
// 94.093 us; speedup vs baseline: 1.1364x; 1.1364x over previous
//
#include <hip/hip_runtime.h>
#include <stdint.h>

typedef unsigned short u16;
typedef __attribute__((ext_vector_type(8))) short short8;
typedef __attribute__((ext_vector_type(4))) float f32x4;
typedef __attribute__((ext_vector_type(2))) uint32_t u32x2;

#define B_      16
#define L_      1024
#define H_      1024
#define G_      128
#define M_TOT   16368            // B*(L-1)
#define K_TOT   3072
#define OUT_SEG 2095104          // M_TOT*G_
#define KL_IDX  (4*OUT_SEG)
#define KL_BLOCKS 2046           // M_TOT / 8 exactly

// ws layout
#define WS_WT_OFF    0           // bf16 W'T [512][3072] = 3,145,728 B
#define WS_BIAS_OFF  3145728     // float[512]
#define WS_PART_OFF  3147776     // float[2046] block partials

__device__ inline u16 f2bf(float f) {
    union { float f; uint32_t u; } x; x.f = f;
    uint32_t u = x.u;
    return (u16)((u + 0x7fffu + ((u >> 16) & 1u)) >> 16);
}

__device__ inline void gload16(const void* g, void* l) {
    __builtin_amdgcn_global_load_lds(
        (const __attribute__((address_space(1))) void*)g,
        (__attribute__((address_space(3))) void*)l, 16, 0, 0);
}

// ---------------- prep: build W'T (bf16, [512][3072]) + bias[512] ------------
__global__ __launch_bounds__(256) void prep_kernel(
    const float* __restrict__ Wzm, const float* __restrict__ bzm,
    const float* __restrict__ Wzv, const float* __restrict__ bzv,
    const float* __restrict__ Wqm, const float* __restrict__ bqm,
    const float* __restrict__ Wqv, const float* __restrict__ bqv,
    u16* __restrict__ wt, float* __restrict__ bias)
{
    const int ng = blockIdx.x >> 2;
    const int kq = blockIdx.x & 3;
    const int n0 = ng * 8;
    const float* W; const float* bsrc; int g0; int kmax;
    if (n0 < 128)      { W = Wzm; bsrc = bzm; g0 = n0;       kmax = 2048; }
    else if (n0 < 256) { W = Wzv; bsrc = bzv; g0 = n0 - 128; kmax = 2048; }
    else if (n0 < 384) { W = Wqm; bsrc = bqm; g0 = n0 - 256; kmax = 3072; }
    else               { W = Wqv; bsrc = bqv; g0 = n0 - 384; kmax = 3072; }
    const int tid = threadIdx.x;
    if (kq == 0 && tid < 8) bias[n0 + tid] = bsrc[g0 + tid];

    __shared__ float lt[8][260];
    const int go = tid & 7;
    const int kk = tid >> 3;
    const int nn = tid >> 5;
    const int kc = (tid & 31) * 8;

    for (int i = 0; i < 3; ++i) {
        int kbase = kq * 768 + i * 256;
        __syncthreads();
        #pragma unroll
        for (int kk2 = 0; kk2 < 8; ++kk2) {
            int k = kbase + kk2 * 32 + kk;
            float v = (k < kmax) ? W[(size_t)k * G_ + g0 + go] : 0.0f;
            lt[go][kk2 * 32 + kk] = v;
        }
        __syncthreads();
        union { short8 s; u16 u[8]; } o;
        #pragma unroll
        for (int j = 0; j < 8; ++j) o.u[j] = f2bf(lt[nn][kc + j]);
        *(short8*)&wt[(size_t)(n0 + nn) * K_TOT + kbase + kc] = o.s;
    }
}

// ---------------- GEMM: out[m, 0:512] = ce @ W' + bias ----------------------
// BM=128, BN=128, BK=64, 512 threads (8 waves, 2x4 grid of 64x32 sub-tiles),
// grid 512 -> 2 blocks/CU = 16 waves/CU (4/SIMD -- double R17's latency
// hiding). Data paths identical to R17/R19:
//   A: global f32x4 (4 threads/row) -> named P/Q reg sets (2-deep) ->
//      cvt_pk bf16 -> swizzled ds_write_b64.
//   B: global_load_lds source-preswizzled.
// LDS = 2*(16KB A + 16KB B) = 64KB. Counted vmcnt: 6 VMEM/thread/phase
// (4 A + 2 B); WAITV(6) drains exactly {B(t), Aregs(t+1)}.
// Swizzle: rows = 128B = 8 chunks of 16B, chunk ^= (row&7).
__global__ __launch_bounds__(512, 2) void gemm_kernel(
    const float* __restrict__ events, const float* __restrict__ contexts,
    const u16* __restrict__ wt, const float* __restrict__ bias,
    float* __restrict__ out)
{
    __shared__ u16 Ab[2][128 * 64];   // bf16 A tiles, swizzled (16 KB each)
    __shared__ u16 Bs[2][128 * 64];   // bf16 B tiles, swizzled (16 KB each)

    const int tid = threadIdx.x;
    const int bid = blockIdx.x;
    // 4 nb-blocks of an A panel share bid&7 -> same XCD.
    const int xx  = bid & 7;
    const int jj  = bid >> 3;            // 0..63
    const int nb  = jj & 3;
    const int mp  = (jj >> 2) * 8 + xx;  // 0..127
    const int m0  = mp * 128;

    const int lane = tid & 63;
    const int w    = tid >> 6;           // 0..7
    const int wm   = (w >> 2) * 64;      // 0 or 64
    const int wn   = (w & 3) * 32;       // 0,32,64,96
    const int lr   = lane & 15;
    const int kg   = lane >> 4;          // octet 0..3

    // ---- A staging: row r = tid>>2 (0..127), quarter q = tid&3 ----
    const int r = tid >> 2;
    const int q = tid & 3;
    int m = m0 + r; if (m > M_TOT - 1) m = M_TOT - 1;
    int bb = m / 1023;
    int tt = m - bb * 1023;
    const float* paE = events   + ((size_t)(bb * L_ + tt)) * H_;
    const float* paC = contexts + ((size_t)(bb * (L_ - 1) + tt)) * H_;
    // swizzled ds_write_b64 offsets: load j -> chunk 2j+(q>>1), +4 if q odd
    int aw[4];
    #pragma unroll
    for (int j = 0; j < 4; ++j)
        aw[j] = r * 64 + (((2 * j + (q >> 1)) ^ (r & 7)) << 3) + (q & 1) * 4;

    // ---- B staging: 2 chunks/thread, source-preswizzled ----
    const u16* bS[2];
    #pragma unroll
    for (int it = 0; it < 2; ++it) {
        int c  = it * 512 + tid;         // 0..1023
        int v  = c >> 3;
        int cs = (c & 7) ^ (v & 7);
        bS[it] = wt + (size_t)(nb * 128 + v) * K_TOT + cs * 8;
    }

    // ---- fragment read offsets (u16, swizzled; chunk cw = ks*4+kg) ----
    int aoff[4][2], boff[2][2];
    #pragma unroll
    for (int i = 0; i < 4; ++i) {
        int row = wm + i * 16 + lr;
        #pragma unroll
        for (int ks = 0; ks < 2; ++ks)
            aoff[i][ks] = row * 64 + (((ks * 4 + kg) ^ (row & 7)) << 3);
    }
    #pragma unroll
    for (int j = 0; j < 2; ++j) {
        int nn = wn + j * 16 + lr;
        #pragma unroll
        for (int ks = 0; ks < 2; ++ks)
            boff[j][ks] = nn * 64 + (((ks * 4 + kg) ^ (nn & 7)) << 3);
    }

    f32x4 acc[4][2];
    #pragma unroll
    for (int i = 0; i < 4; ++i)
        #pragma unroll
        for (int j = 0; j < 2; ++j)
            acc[i][j] = (f32x4){0.f, 0.f, 0.f, 0.f};

    auto stageB = [&](int buf, int kt) {
        int k0 = kt * 64;
        gload16(bS[0] + k0, &Bs[buf][tid * 8]);
        gload16(bS[1] + k0, &Bs[buf][(512 + tid) * 8]);
    };
    auto compute = [&](int buf) {
        #pragma unroll
        for (int ks = 0; ks < 2; ++ks) {
            short8 a[4], bf[2];
            #pragma unroll
            for (int i = 0; i < 4; ++i)
                a[i] = *(const short8*)&Ab[buf][aoff[i][ks]];
            #pragma unroll
            for (int j = 0; j < 2; ++j)
                bf[j] = *(const short8*)&Bs[buf][boff[j][ks]];
            __builtin_amdgcn_s_setprio(1);
            #pragma unroll
            for (int i = 0; i < 4; ++i)
                #pragma unroll
                for (int j = 0; j < 2; ++j)
                    acc[i][j] = __builtin_amdgcn_mfma_f32_16x16x32_bf16(
                        a[i], bf[j], acc[i][j], 0, 0, 0);
            __builtin_amdgcn_s_setprio(0);
        }
    };

    // Named A-staging register sets (2-phase-deep; no arrays -> no scratch)
    f32x4 P0, P1, P2, P3;
    f32x4 Q0, Q1, Q2, Q3;

#define LOADA(p, KT)                                                           \
    {                                                                          \
        int k0_ = (KT) * 64;                                                   \
        int rg_ = (KT) >> 4;                                                   \
        int kq_ = (k0_ & 1023) + q * 4;                                        \
        const float* s_ = (rg_ == 0) ? paE : (rg_ == 1 ? (paE + H_) : paC);    \
        s_ += kq_;                                                             \
        p##0 = *(const f32x4*)(s_ +  0);                                       \
        p##1 = *(const f32x4*)(s_ + 16);                                       \
        p##2 = *(const f32x4*)(s_ + 32);                                       \
        p##3 = *(const f32x4*)(s_ + 48);                                       \
    }
#define CVT1(p, J, BUF)                                                        \
    {                                                                          \
        uint32_t lo_, hi_;                                                     \
        asm("v_cvt_pk_bf16_f32 %0, %1, %2" : "=v"(lo_) : "v"(p##J[0]), "v"(p##J[1])); \
        asm("v_cvt_pk_bf16_f32 %0, %1, %2" : "=v"(hi_) : "v"(p##J[2]), "v"(p##J[3])); \
        *(u32x2*)&Ab[BUF][aw[J]] = (u32x2){lo_, hi_};                          \
    }
#define CVTW(p, BUF)  CVT1(p, 0, BUF) CVT1(p, 1, BUF) CVT1(p, 2, BUF) CVT1(p, 3, BUF)

#define WAITV(N)                                                               \
    asm volatile("s_waitcnt vmcnt(" #N ")" ::: "memory");                      \
    __builtin_amdgcn_sched_barrier(0);
#define LGKM0                                                                  \
    asm volatile("s_waitcnt lgkmcnt(0)" ::: "memory");                         \
    __builtin_amdgcn_sched_barrier(0);
#define BAR __builtin_amdgcn_s_barrier()

    // prologue: A(0)->regs->Ab[0]; B(0) in flight; A(1)->Q (in flight)
    LOADA(P, 0);
    stageB(0, 0);
    WAITV(2);            // drain P = A(0) regs, leave B(0)
    CVTW(P, 0);
    LOADA(Q, 1);         // outstanding: B(0) 2 + Q 4 = 6
    LGKM0;               // prologue ds_writes done before first barrier

    for (int t = 0; t < 46; t += 2) {
        // phase t (buf0): consume Q=A(t+1) after WAITV
        LOADA(P, t + 2);
        stageB(1, t + 1);
        WAITV(6); BAR;                 // drains B(t) + Q regs
        compute(0);
        CVTW(Q, 1);
        LGKM0; BAR;
        // phase t+1 (buf1)
        LOADA(Q, t + 3);
        stageB(0, t + 2);
        WAITV(6); BAR;                 // drains B(t+1) + P regs
        compute(1);
        CVTW(P, 0);
        LGKM0; BAR;
    }
    // phase 46 (buf0): Q holds A(47); no more A loads
    stageB(1, 47);
    WAITV(2); BAR;                     // drains B(46) + Q regs, leaves B(47)
    compute(0);
    CVTW(Q, 1);
    LGKM0; BAR;
    // phase 47 (buf1)
    WAITV(0); BAR;
    compute(1);

#undef LOADA
#undef CVT1
#undef CVTW
#undef WAITV
#undef LGKM0
#undef BAR

    // epilogue: row = m0 + wm + i*16 + kg*4 + rr ; gcol = nb*128 + wn + j*16 + lr
    const float* bptr = bias + nb * 128;
    float* obase = out + (size_t)nb * OUT_SEG;
    #pragma unroll
    for (int i = 0; i < 4; ++i) {
        int mloc = wm + i * 16 + kg * 4;
        #pragma unroll
        for (int j = 0; j < 2; ++j) {
            int g = wn + j * 16 + lr;
            float bv = bptr[g];
            #pragma unroll
            for (int rr = 0; rr < 4; ++rr) {
                int mo = m0 + mloc + rr;
                if (mo < M_TOT) obase[(size_t)mo * G_ + g] = acc[i][j][rr] + bv;
            }
        }
    }
}

// ---------------- KL reduction: stage 1 (f32x4 loads, 8 rows/block) ----------
__global__ __launch_bounds__(256) void kl_kernel(const float* __restrict__ out,
                                                 float* __restrict__ partial)
{
    int row  = blockIdx.x * 8 + (threadIdx.x >> 5);   // 2046*8 = M_TOT
    int col  = (threadIdx.x & 31) * 4;
    const float* zm  = out;
    const float* zlv = out + OUT_SEG;
    const float* qm  = out + (size_t)2 * OUT_SEG;
    const float* qlv = out + (size_t)3 * OUT_SEG;
    size_t base = (size_t)row * G_ + col;
    f32x4 a = *(const f32x4*)&zm[base];
    f32x4 b = *(const f32x4*)&zlv[base];
    f32x4 c = *(const f32x4*)&qm[base];
    f32x4 d = *(const f32x4*)&qlv[base];
    float s = 0.f;
    #pragma unroll
    for (int e = 0; e < 4; ++e) {
        float diff = a[e] - c[e];
        s += d[e] - b[e] + (__expf(b[e]) + diff * diff) * __expf(-d[e]) - 1.0f;
    }
    #pragma unroll
    for (int off = 32; off > 0; off >>= 1)
        s += __shfl_down(s, off);
    __shared__ float pw[4];
    int wid  = threadIdx.x >> 6;
    int lane = threadIdx.x & 63;
    if (lane == 0) pw[wid] = s;
    __syncthreads();
    if (threadIdx.x == 0)
        partial[blockIdx.x] = pw[0] + pw[1] + pw[2] + pw[3];
}

// ---------------- KL reduction: stage 2 --------------------------------------
__global__ __launch_bounds__(256) void kl_final(const float* __restrict__ partial,
                                                float* __restrict__ out)
{
    float s = 0.f;
    for (int i = threadIdx.x; i < KL_BLOCKS; i += 256) s += partial[i];
    #pragma unroll
    for (int off = 32; off > 0; off >>= 1)
        s += __shfl_down(s, off);
    __shared__ float pw[4];
    int wid = threadIdx.x >> 6;
    int lane = threadIdx.x & 63;
    if (lane == 0) pw[wid] = s;
    __syncthreads();
    if (threadIdx.x == 0)
        out[KL_IDX] = 0.5f * (pw[0] + pw[1] + pw[2] + pw[3]) / (float)M_TOT;
}

// ---------------- launcher ----------------------------------------------------
extern "C" void kernel_launch(void* const* d_in, const int* in_sizes, int n_in,
                              void* d_out, int out_size, void* d_ws, size_t ws_size,
                              hipStream_t stream)
{
    const float* events   = (const float*)d_in[0];
    const float* contexts = (const float*)d_in[1];
    const float* Wzm = (const float*)d_in[2];
    const float* bzm = (const float*)d_in[3];
    const float* Wzv = (const float*)d_in[4];
    const float* bzv = (const float*)d_in[5];
    const float* Wqm = (const float*)d_in[6];
    const float* bqm = (const float*)d_in[7];
    const float* Wqv = (const float*)d_in[8];
    const float* bqv = (const float*)d_in[9];
    float* out = (float*)d_out;

    u16*   wt      = (u16*)((char*)d_ws + WS_WT_OFF);
    float* bias    = (float*)((char*)d_ws + WS_BIAS_OFF);
    float* partial = (float*)((char*)d_ws + WS_PART_OFF);

    prep_kernel<<<256, 256, 0, stream>>>(Wzm, bzm, Wzv, bzv, Wqm, bqm, Wqv, bqv,
                                         wt, bias);
    gemm_kernel<<<512, 512, 0, stream>>>(events, contexts, wt, bias, out);
    kl_kernel<<<KL_BLOCKS, 256, 0, stream>>>(out, partial);
    kl_final<<<1, 256, 0, stream>>>(partial, out);
}